// Round 11
// baseline (102.531 us; speedup 1.0000x reference)
//
#include <hip/hip_runtime.h>
#include <hip/hip_bf16.h>
#include <cmath>

#define B_   4
#define NT_  2048
#define G_   4096
#define DZ_  128

typedef __attribute__((ext_vector_type(8))) short bf16x8;
typedef __attribute__((ext_vector_type(8))) short s16x8;
typedef __attribute__((ext_vector_type(4))) float f32x4;

__device__ __forceinline__ float softplus_f(float x) {
    return fmaxf(x, 0.0f) + log1pf(expf(-fabsf(x)));
}

// async 16B global -> LDS (lane i lands at ldst + 16*i; ldst wave-uniform)
__device__ __forceinline__ void gl2lds16(const void* gsrc, void* ldst) {
    __builtin_amdgcn_global_load_lds(
        (const __attribute__((address_space(1))) unsigned int*)gsrc,
        (__attribute__((address_space(3))) unsigned int*)ldst, 16, 0, 0);
}

// z_grid (B,G,DZ) fp32 -> Zt3 FRAG-MAJOR bf16 tiles (v9 layout, unchanged):
//   Zt3[ ((b*128 + c)*8 + nt)*512 + (q*16 + l15)*8 + j ]
// MFMA B-frag ds_read_b128 at mytile + nt*512 + lane*8 = conflict-free.
// Each 8 KB chunk-tile contiguous; gl2lds16 i writes exactly frag i (1 KB).
__global__ __launch_bounds__(256, 1)
void transpose_z(const float* __restrict__ z, unsigned short* __restrict__ zt)
{
    __shared__ unsigned short tile[64][66];
    const int bx = blockIdx.x;                // 4b * 64gt * 2zt = 512
    const int zti = bx & 1;
    const int gt  = (bx >> 1) & 63;
    const int b   = bx >> 7;
    const int g0 = gt * 64, z0 = zti * 64;
    const int tid = threadIdx.x;
    const int zl = tid & 63, gl = tid >> 6;
    #pragma unroll
    for (int i = 0; i < 16; ++i) {
        const int g = gl + i * 4;
        const float v = z[(size_t)(b * G_ + g0 + g) * DZ_ + z0 + zl];
        unsigned int u = __float_as_uint(v);
        u = u + 0x7FFFu + ((u >> 16) & 1u);   // RNE to bf16
        tile[g][zl] = (unsigned short)(u >> 16);
    }
    __syncthreads();
    const int nt  = tid >> 6;                 // frag (z-block) 0..3 (local)
    const int q   = (tid >> 4) & 3;           // g-octet within chunk
    const int fl  = tid & 15;                 // l15 (z within frag)
    #pragma unroll
    for (int i = 0; i < 2; ++i) {             // chunk-local (c = gt*2 + i)
        s16x8 v;
        #pragma unroll
        for (int j = 0; j < 8; ++j)
            v[j] = (short)tile[i * 32 + q * 8 + j][nt * 16 + fl];
        *(s16x8*)(zt + ((size_t)(b * 128 + gt * 2 + i) * 8 + zti * 4 + nt) * 512
                  + (size_t)(q * 16 + fl) * 8) = v;
    }
}

// v10: v9 + SPLIT DRAIN with counted vmcnt (T4).  gl2lds16 i <-> frag i, so:
//   vmcnt(4) -> consume frags 0-3 -> xv(ch+1) + stage(ch+1) frags 0-3
//   -> vmcnt(8) (retires exactly S(ch) frags 4-7; leaves xv + S' in flight)
//   -> consume frags 4-7 -> stage frags 4-7.
// Steady-state queue at chunk entry: [X(ch) 4, S(ch) 8]; weights' implicit
// xv wait = vmcnt(8) leaves S(ch) in flight.  Every DMA gets >= one full
// phase of lead; no full drain anywhere except the last chunk's tail.
// Zero new registers vs v9.
__global__ __launch_bounds__(512, 4)
void setconv_main(const float* __restrict__ xt,
                  const float* __restrict__ xg,
                  const float* __restrict__ lsp,
                  const unsigned short* __restrict__ Zt,
                  float* __restrict__ out)
{
    __shared__ __align__(16) unsigned short lds[32768];  // 64 KB: 8 wave-tiles / red

    // XCD swizzle: bx = tt2*8 + b*2 + p -> same-b blocks on 2 XCDs
    const int bx = blockIdx.x;
    const int b  = (bx >> 1) & 3;
    const int tt = ((bx >> 3) << 1) | (bx & 1);   // 0..127
    const int tid  = threadIdx.x;
    const int w    = tid >> 6;                // = kh, 0..7
    const int lane = tid & 63;
    const int quad = lane >> 4;
    const int l15  = lane & 15;
    const int t0   = tt * 16;

    float c00, c01, c10, c11;
    {
        const float h = -0.72134752f;         // -0.5*log2(e)
        float ls;
        ls = 1e-5f + softplus_f(lsp[0]); c00 = h / (ls * ls);
        ls = 1e-5f + softplus_f(lsp[1]); c01 = h / (ls * ls);
        ls = 1e-5f + softplus_f(lsp[2]); c10 = h / (ls * ls);
        ls = 1e-5f + softplus_f(lsp[3]); c11 = h / (ls * ls);
    }

    // A-frag row m = l15 -> per-lane t constants
    const float xt0 = xt[(size_t)(b * NT_ + t0 + l15) * 2 + 0];
    const float xt1 = xt[(size_t)(b * NT_ + t0 + l15) * 2 + 1];

    f32x4 acc[2][8];
    #pragma unroll
    for (int k = 0; k < 2; ++k)
        #pragma unroll
        for (int n = 0; n < 8; ++n) acc[k][n] = (f32x4)0.0f;

    unsigned short* const mytile = lds + w * 4096;       // private 8 KB slot
    const float* xgq = xg + (size_t)(b * G_ + w * 512 + quad * 8) * 2;
    const unsigned short* zs0 = Zt + (size_t)(b * 128 + w * 16) * 4096 + lane * 8;

    // prologue: xv(0) first (oldest), then stage(0) all 8 frags
    float4 xv0 = *(const float4*)(xgq + 0);
    float4 xv1 = *(const float4*)(xgq + 4);
    float4 xv2 = *(const float4*)(xgq + 8);
    float4 xv3 = *(const float4*)(xgq + 12);
    #pragma unroll
    for (int i = 0; i < 8; ++i)
        gl2lds16(zs0 + i * 512, mytile + i * 512);

    #pragma unroll
    for (int ch = 0; ch < 16; ++ch) {
        // ---- weights(ch) from xv (implicit wait leaves S(ch) in flight) ----
        float gx[8], gy[8];
        gx[0]=xv0.x; gy[0]=xv0.y; gx[1]=xv0.z; gy[1]=xv0.w;
        gx[2]=xv1.x; gy[2]=xv1.y; gx[3]=xv1.z; gy[3]=xv1.w;
        gx[4]=xv2.x; gy[4]=xv2.y; gx[5]=xv2.z; gy[5]=xv2.w;
        gx[6]=xv3.x; gy[6]=xv3.y; gx[7]=xv3.z; gy[7]=xv3.w;
        unsigned int w0b[8], w1b[8];
        #pragma unroll
        for (int j = 0; j < 8; ++j) {
            const float d0 = xt0 - gx[j];
            const float d1 = xt1 - gy[j];
            const float q0 = d0 * d0;
            const float q1 = d1 * d1;
            const float e0 = fmaf(q1, c10, q0 * c00);
            const float e1 = fmaf(q1, c11, q0 * c01);
            w0b[j] = __float_as_uint(__builtin_amdgcn_exp2f(e0));
            w1b[j] = __float_as_uint(__builtin_amdgcn_exp2f(e1));
        }
        union { bf16x8 v; unsigned int u[4]; } a0, a1;
        #pragma unroll
        for (int h = 0; h < 4; ++h) {
            a0.u[h] = __builtin_amdgcn_perm(w0b[2*h+1], w0b[2*h], 0x07060302u);
            a1.u[h] = __builtin_amdgcn_perm(w1b[2*h+1], w1b[2*h], 0x07060302u);
        }

        // ---- first-half drain: S(ch) frags 0-3 only ----
        __builtin_amdgcn_s_waitcnt(0x0F74);          // vmcnt(4)
        #pragma unroll
        for (int nt = 0; nt < 4; ++nt) {
            const bf16x8 bz = *(const bf16x8*)(mytile + nt * 512 + lane * 8);
            acc[0][nt] = __builtin_amdgcn_mfma_f32_16x16x32_bf16(a0.v, bz, acc[0][nt], 0, 0, 0);
            acc[1][nt] = __builtin_amdgcn_mfma_f32_16x16x32_bf16(a1.v, bz, acc[1][nt], 0, 0, 0);
        }

        // ---- xv(ch+1) + stage(ch+1) frags 0-3 into the consumed half ----
        if (ch < 15) {
            const float* xp = xgq + (ch + 1) * 64;
            xv0 = *(const float4*)(xp + 0);
            xv1 = *(const float4*)(xp + 4);
            xv2 = *(const float4*)(xp + 8);
            xv3 = *(const float4*)(xp + 12);
            const unsigned short* zs = zs0 + (size_t)(ch + 1) * 4096;
            #pragma unroll
            for (int i = 0; i < 4; ++i)
                gl2lds16(zs + i * 512, mytile + i * 512);
        }

        // ---- second-half drain: retires exactly S(ch) frags 4-7 ----
        if (ch < 15)
            __builtin_amdgcn_s_waitcnt(0x0F78);      // vmcnt(8): [X',S'0-3] stay
        else
            __builtin_amdgcn_s_waitcnt(0x0F70);      // tail: vmcnt(0)
        #pragma unroll
        for (int nt = 4; nt < 8; ++nt) {
            const bf16x8 bz = *(const bf16x8*)(mytile + nt * 512 + lane * 8);
            acc[0][nt] = __builtin_amdgcn_mfma_f32_16x16x32_bf16(a0.v, bz, acc[0][nt], 0, 0, 0);
            acc[1][nt] = __builtin_amdgcn_mfma_f32_16x16x32_bf16(a1.v, bz, acc[1][nt], 0, 0, 0);
        }

        // ---- stage(ch+1) frags 4-7 ----
        if (ch < 15) {
            const unsigned short* zs = zs0 + (size_t)(ch + 1) * 4096;
            #pragma unroll
            for (int i = 4; i < 8; ++i)
                gl2lds16(zs + i * 512, mytile + i * 512);
        }
    }

    // ---- 3-round k-reduction over the 8 kh-waves (aliases wave tiles) ----
    float* const red = (float*)lds;
    #define RED_W(slot) { \
        float* bp = &red[(slot) * 4096 + lane * 4]; \
        _Pragma("unroll") \
        for (int k = 0; k < 2; ++k) \
            _Pragma("unroll") \
            for (int n = 0; n < 8; ++n) \
                *(f32x4*)(bp + (k * 8 + n) * 256) = acc[k][n]; }
    #define RED_A(slot) { \
        const float* bp = &red[(slot) * 4096 + lane * 4]; \
        _Pragma("unroll") \
        for (int k = 0; k < 2; ++k) \
            _Pragma("unroll") \
            for (int n = 0; n < 8; ++n) \
                acc[k][n] += *(const f32x4*)(bp + (k * 8 + n) * 256); }

    __syncthreads();
    if (w >= 4) RED_W(w - 4);
    __syncthreads();
    if (w < 4) RED_A(w);
    if (w == 2 || w == 3) RED_W(w);
    __syncthreads();
    if (w < 2) RED_A(w + 2);
    if (w == 1) RED_W(3);
    __syncthreads();
    if (w == 0) {
        RED_A(3);
        const int tr = t0 + quad * 4;
        #pragma unroll
        for (int nt = 0; nt < 8; ++nt) {
            float* ob = out + (size_t)(b * NT_ + tr) * (DZ_ * 2) + (nt * 16 + l15) * 2;
            #pragma unroll
            for (int r = 0; r < 4; ++r)
                *(float2*)(ob + (size_t)r * (DZ_ * 2)) =
                    make_float2(acc[0][nt][r], acc[1][nt][r]);
        }
    }
    #undef RED_W
    #undef RED_A
}

extern "C" void kernel_launch(void* const* d_in, const int* in_sizes, int n_in,
                              void* d_out, int out_size, void* d_ws, size_t ws_size,
                              hipStream_t stream)
{
    const float* x_grid = (const float*)d_in[0];   // (4,64,64,2)
    const float* z_grid = (const float*)d_in[1];   // (4,64,64,128)
    const float* xt     = (const float*)d_in[2];   // (4,2048,2)
    const float* lsp    = (const float*)d_in[3];   // (2,2)
    float* out = (float*)d_out;                    // (4,2048,256) fp32
    unsigned short* Zt = (unsigned short*)d_ws;    // tiled, 4 MB

    hipLaunchKernelGGL(transpose_z, dim3(512), dim3(256), 0, stream, z_grid, Zt);
    hipLaunchKernelGGL(setconv_main, dim3(512), dim3(512), 0, stream,
                       xt, x_grid, lsp, Zt, out);
}

// Round 12
// 101.705 us; speedup vs baseline: 1.0081x; 1.0081x over previous
//
#include <hip/hip_runtime.h>
#include <hip/hip_bf16.h>
#include <cmath>

#define B_   4
#define NT_  2048
#define G_   4096
#define DZ_  128

typedef __attribute__((ext_vector_type(8))) short bf16x8;
typedef __attribute__((ext_vector_type(8))) short s16x8;
typedef __attribute__((ext_vector_type(4))) float f32x4;

__device__ __forceinline__ float softplus_f(float x) {
    return fmaxf(x, 0.0f) + log1pf(expf(-fabsf(x)));
}

// async 16B global -> LDS (lane i lands at ldst + 16*i; ldst wave-uniform)
__device__ __forceinline__ void gl2lds16(const void* gsrc, void* ldst) {
    __builtin_amdgcn_global_load_lds(
        (const __attribute__((address_space(1))) unsigned int*)gsrc,
        (__attribute__((address_space(3))) unsigned int*)ldst, 16, 0, 0);
}

// z_grid (B,G,DZ) fp32 -> Zt3 FRAG-MAJOR bf16 tiles (v9 layout, unchanged):
//   Zt3[ ((b*128 + c)*8 + nt)*512 + (q*16 + l15)*8 + j ]
// MFMA B-frag ds_read_b128 at mytile + nt*512 + lane*8 = conflict-free.
__global__ __launch_bounds__(256, 1)
void transpose_z(const float* __restrict__ z, unsigned short* __restrict__ zt)
{
    __shared__ unsigned short tile[64][66];
    const int bx = blockIdx.x;                // 4b * 64gt * 2zt = 512
    const int zti = bx & 1;
    const int gt  = (bx >> 1) & 63;
    const int b   = bx >> 7;
    const int g0 = gt * 64, z0 = zti * 64;
    const int tid = threadIdx.x;
    const int zl = tid & 63, gl = tid >> 6;
    #pragma unroll
    for (int i = 0; i < 16; ++i) {
        const int g = gl + i * 4;
        const float v = z[(size_t)(b * G_ + g0 + g) * DZ_ + z0 + zl];
        unsigned int u = __float_as_uint(v);
        u = u + 0x7FFFu + ((u >> 16) & 1u);   // RNE to bf16
        tile[g][zl] = (unsigned short)(u >> 16);
    }
    __syncthreads();
    const int nt  = tid >> 6;                 // frag (z-block) 0..3 (local)
    const int q   = (tid >> 4) & 3;           // g-octet within chunk
    const int fl  = tid & 15;                 // l15 (z within frag)
    #pragma unroll
    for (int i = 0; i < 2; ++i) {             // chunk-local (c = gt*2 + i)
        s16x8 v;
        #pragma unroll
        for (int j = 0; j < 8; ++j)
            v[j] = (short)tile[i * 32 + q * 8 + j][nt * 16 + fl];
        *(s16x8*)(zt + ((size_t)(b * 128 + gt * 2 + i) * 8 + zti * 4 + nt) * 512
                  + (size_t)(q * 16 + fl) * 8) = v;
    }
}

// v12: v10 + (1) weight transient halved (two j-groups of 4, pack
// immediately: live set ~48 -> ~32 regs => deeper load pipelining at the
// 128-reg/wave cap), (2) s_setprio(1) around MFMA consume clusters
// (independent-wave regime: measured +4-7% on attn-like schedules),
// (3) reduction 4 barriers -> 3 (wave0 serially accumulates 3 slots).
// Split-drain counted vmcnt retained from v10 (measured neutral, principled).
__global__ __launch_bounds__(512, 4)
void setconv_main(const float* __restrict__ xt,
                  const float* __restrict__ xg,
                  const float* __restrict__ lsp,
                  const unsigned short* __restrict__ Zt,
                  float* __restrict__ out)
{
    __shared__ __align__(16) unsigned short lds[32768];  // 64 KB: 8 wave-tiles / red

    // XCD swizzle: bx = tt2*8 + b*2 + p -> same-b blocks on 2 XCDs
    const int bx = blockIdx.x;
    const int b  = (bx >> 1) & 3;
    const int tt = ((bx >> 3) << 1) | (bx & 1);   // 0..127
    const int tid  = threadIdx.x;
    const int w    = tid >> 6;                // = kh, 0..7
    const int lane = tid & 63;
    const int quad = lane >> 4;
    const int l15  = lane & 15;
    const int t0   = tt * 16;

    float c00, c01, c10, c11;
    {
        const float h = -0.72134752f;         // -0.5*log2(e)
        float ls;
        ls = 1e-5f + softplus_f(lsp[0]); c00 = h / (ls * ls);
        ls = 1e-5f + softplus_f(lsp[1]); c01 = h / (ls * ls);
        ls = 1e-5f + softplus_f(lsp[2]); c10 = h / (ls * ls);
        ls = 1e-5f + softplus_f(lsp[3]); c11 = h / (ls * ls);
    }

    // A-frag row m = l15 -> per-lane t constants
    const float xt0 = xt[(size_t)(b * NT_ + t0 + l15) * 2 + 0];
    const float xt1 = xt[(size_t)(b * NT_ + t0 + l15) * 2 + 1];

    f32x4 acc[2][8];
    #pragma unroll
    for (int k = 0; k < 2; ++k)
        #pragma unroll
        for (int n = 0; n < 8; ++n) acc[k][n] = (f32x4)0.0f;

    unsigned short* const mytile = lds + w * 4096;       // private 8 KB slot
    const float* xgq = xg + (size_t)(b * G_ + w * 512 + quad * 8) * 2;
    const unsigned short* zs0 = Zt + (size_t)(b * 128 + w * 16) * 4096 + lane * 8;

    // prologue: xv(0) first (oldest), then stage(0) all 8 frags
    float4 xv0 = *(const float4*)(xgq + 0);
    float4 xv1 = *(const float4*)(xgq + 4);
    float4 xv2 = *(const float4*)(xgq + 8);
    float4 xv3 = *(const float4*)(xgq + 12);
    #pragma unroll
    for (int i = 0; i < 8; ++i)
        gl2lds16(zs0 + i * 512, mytile + i * 512);

    #pragma unroll
    for (int ch = 0; ch < 16; ++ch) {
        // ---- weights(ch): two j-groups of 4, packed immediately ----
        union { bf16x8 v; unsigned int u[4]; } a0, a1;
        #pragma unroll
        for (int jg = 0; jg < 2; ++jg) {
            const float4 xva = (jg == 0) ? xv0 : xv2;
            const float4 xvb = (jg == 0) ? xv1 : xv3;
            float gx[4], gy[4];
            gx[0]=xva.x; gy[0]=xva.y; gx[1]=xva.z; gy[1]=xva.w;
            gx[2]=xvb.x; gy[2]=xvb.y; gx[3]=xvb.z; gy[3]=xvb.w;
            unsigned int w0b[4], w1b[4];
            #pragma unroll
            for (int j = 0; j < 4; ++j) {
                const float d0 = xt0 - gx[j];
                const float d1 = xt1 - gy[j];
                const float q0 = d0 * d0;
                const float q1 = d1 * d1;
                const float e0 = fmaf(q1, c10, q0 * c00);
                const float e1 = fmaf(q1, c11, q0 * c01);
                w0b[j] = __float_as_uint(__builtin_amdgcn_exp2f(e0));
                w1b[j] = __float_as_uint(__builtin_amdgcn_exp2f(e1));
            }
            #pragma unroll
            for (int h = 0; h < 2; ++h) {
                a0.u[jg * 2 + h] = __builtin_amdgcn_perm(w0b[2*h+1], w0b[2*h], 0x07060302u);
                a1.u[jg * 2 + h] = __builtin_amdgcn_perm(w1b[2*h+1], w1b[2*h], 0x07060302u);
            }
        }

        // ---- first-half drain: S(ch) frags 0-3 only ----
        __builtin_amdgcn_s_waitcnt(0x0F74);          // vmcnt(4)
        __builtin_amdgcn_s_setprio(1);
        #pragma unroll
        for (int nt = 0; nt < 4; ++nt) {
            const bf16x8 bz = *(const bf16x8*)(mytile + nt * 512 + lane * 8);
            acc[0][nt] = __builtin_amdgcn_mfma_f32_16x16x32_bf16(a0.v, bz, acc[0][nt], 0, 0, 0);
            acc[1][nt] = __builtin_amdgcn_mfma_f32_16x16x32_bf16(a1.v, bz, acc[1][nt], 0, 0, 0);
        }
        __builtin_amdgcn_s_setprio(0);

        // ---- xv(ch+1) + stage(ch+1) frags 0-3 into the consumed half ----
        if (ch < 15) {
            const float* xp = xgq + (ch + 1) * 64;
            xv0 = *(const float4*)(xp + 0);
            xv1 = *(const float4*)(xp + 4);
            xv2 = *(const float4*)(xp + 8);
            xv3 = *(const float4*)(xp + 12);
            const unsigned short* zs = zs0 + (size_t)(ch + 1) * 4096;
            #pragma unroll
            for (int i = 0; i < 4; ++i)
                gl2lds16(zs + i * 512, mytile + i * 512);
        }

        // ---- second-half drain: retires exactly S(ch) frags 4-7 ----
        if (ch < 15)
            __builtin_amdgcn_s_waitcnt(0x0F78);      // vmcnt(8): [X',S'0-3] stay
        else
            __builtin_amdgcn_s_waitcnt(0x0F70);      // tail: vmcnt(0)
        __builtin_amdgcn_s_setprio(1);
        #pragma unroll
        for (int nt = 4; nt < 8; ++nt) {
            const bf16x8 bz = *(const bf16x8*)(mytile + nt * 512 + lane * 8);
            acc[0][nt] = __builtin_amdgcn_mfma_f32_16x16x32_bf16(a0.v, bz, acc[0][nt], 0, 0, 0);
            acc[1][nt] = __builtin_amdgcn_mfma_f32_16x16x32_bf16(a1.v, bz, acc[1][nt], 0, 0, 0);
        }
        __builtin_amdgcn_s_setprio(0);

        // ---- stage(ch+1) frags 4-7 ----
        if (ch < 15) {
            const unsigned short* zs = zs0 + (size_t)(ch + 1) * 4096;
            #pragma unroll
            for (int i = 4; i < 8; ++i)
                gl2lds16(zs + i * 512, mytile + i * 512);
        }
    }

    // ---- 2-round k-reduction over the 8 kh-waves (3 barriers total) ----
    float* const red = (float*)lds;
    #define RED_W(slot) { \
        float* bp = &red[(slot) * 4096 + lane * 4]; \
        _Pragma("unroll") \
        for (int k = 0; k < 2; ++k) \
            _Pragma("unroll") \
            for (int n = 0; n < 8; ++n) \
                *(f32x4*)(bp + (k * 8 + n) * 256) = acc[k][n]; }
    #define RED_A(slot) { \
        const float* bp = &red[(slot) * 4096 + lane * 4]; \
        _Pragma("unroll") \
        for (int k = 0; k < 2; ++k) \
            _Pragma("unroll") \
            for (int n = 0; n < 8; ++n) \
                acc[k][n] += *(const f32x4*)(bp + (k * 8 + n) * 256); }

    __syncthreads();                          // all waves done with tiles
    if (w >= 4) RED_W(w - 4);                 // w4..7 -> slots 0..3
    __syncthreads();
    if (w < 4) RED_A(w);                      // w0..3 += slots 0..3
    if (w >= 1 && w < 4) RED_W(w - 1);        // w1..3 -> slots 0..2
    __syncthreads();
    if (w == 0) {
        RED_A(0); RED_A(1); RED_A(2);         // serial 3-slot accumulate
        const int tr = t0 + quad * 4;
        #pragma unroll
        for (int nt = 0; nt < 8; ++nt) {
            float* ob = out + (size_t)(b * NT_ + tr) * (DZ_ * 2) + (nt * 16 + l15) * 2;
            #pragma unroll
            for (int r = 0; r < 4; ++r)
                *(float2*)(ob + (size_t)r * (DZ_ * 2)) =
                    make_float2(acc[0][nt][r], acc[1][nt][r]);
        }
    }
    #undef RED_W
    #undef RED_A
}

extern "C" void kernel_launch(void* const* d_in, const int* in_sizes, int n_in,
                              void* d_out, int out_size, void* d_ws, size_t ws_size,
                              hipStream_t stream)
{
    const float* x_grid = (const float*)d_in[0];   // (4,64,64,2)
    const float* z_grid = (const float*)d_in[1];   // (4,64,64,128)
    const float* xt     = (const float*)d_in[2];   // (4,2048,2)
    const float* lsp    = (const float*)d_in[3];   // (2,2)
    float* out = (float*)d_out;                    // (4,2048,256) fp32
    unsigned short* Zt = (unsigned short*)d_ws;    // tiled, 4 MB

    hipLaunchKernelGGL(transpose_z, dim3(512), dim3(256), 0, stream, z_grid, Zt);
    hipLaunchKernelGGL(setconv_main, dim3(512), dim3(512), 0, stream,
                       xt, x_grid, lsp, Zt, out);
}